// Round 4
// baseline (159.625 us; speedup 1.0000x reference)
//
#include <hip/hip_runtime.h>
#include <hip/hip_fp16.h>

// Problem constants (match reference)
#define BB 8
#define NN 1024
#define IN_DIM 512
#define HH 8
#define SUP 64
#define HS (HH * SUP)   // 512

typedef _Float16 half8 __attribute__((ext_vector_type(8)));
typedef _Float16 half4v __attribute__((ext_vector_type(4)));
typedef _Float16 half2v __attribute__((ext_vector_type(2)));
typedef float floatx4 __attribute__((ext_vector_type(4)));

// ---------------------------------------------------------------------------
// kprep: grid-split kernel.
//   [0,2048):    pack A[b][n][m] fp32 (0/1) -> bitmask Am[row][128 B]
//   [2048,2112): W[h][i][o] fp32 -> Wt[h][o][i] fp16 (transpose+cvt)
//   [2112,2240): X fp32 -> Xh fp16 (straight cast, same layout)
// block 256.
// ---------------------------------------------------------------------------
__global__ __launch_bounds__(256) void kprep(const float* __restrict__ A,
                                             unsigned char* __restrict__ Am,
                                             const float* __restrict__ W,
                                             _Float16* __restrict__ Wt,
                                             const float* __restrict__ X,
                                             _Float16* __restrict__ Xh) {
    __shared__ float tile[64][65];
    const int bid = blockIdx.x;
    const int t   = threadIdx.x;
    if (bid < 2048) {
        // ---- pack A ----
        const int gw   = bid * 4 + (t >> 6);   // row = b*N+n
        const int lane = t & 63;
        const float* arow = A + (size_t)gw * NN;
        unsigned long long keep = 0;
#pragma unroll
        for (int g = 0; g < 16; g++) {
            float a = arow[g * 64 + lane];
            unsigned long long bal = __ballot(a > 0.5f);
            if (lane == g) keep = bal;
        }
        if (lane < 16)
            *(unsigned long long*)(Am + (size_t)gw * 128 + lane * 8) = keep;
    } else if (bid < 2112) {
        // ---- transpose W ----
        const int wb = bid - 2048;
        const int it = wb & 7;
        const int h  = wb >> 3;
        {
            const int i  = t >> 2;
            const int o0 = (t & 3) * 16;
            const float* src = W + ((size_t)h * IN_DIM + it * 64 + i) * SUP + o0;
#pragma unroll
            for (int j = 0; j < 4; j++) {
                float4 v = ((const float4*)src)[j];
                tile[i][o0 + j * 4 + 0] = v.x;
                tile[i][o0 + j * 4 + 1] = v.y;
                tile[i][o0 + j * 4 + 2] = v.z;
                tile[i][o0 + j * 4 + 3] = v.w;
            }
        }
        __syncthreads();
        {
            const int o  = t >> 2;
            const int i0 = (t & 3) * 16;
            _Float16 buf[16];
#pragma unroll
            for (int j = 0; j < 16; j++) buf[j] = (_Float16)tile[i0 + j][o];
            _Float16* dst = Wt + ((size_t)h * SUP + o) * IN_DIM + it * 64 + i0;
            *(half8*)dst       = *(half8*)buf;
            *(half8*)(dst + 8) = *(half8*)(buf + 8);
        }
    } else {
        // ---- X fp32 -> fp16 ----  4,194,304 elems / 128 blocks / 256 thr = 128/thread
        const int xb = bid - 2112;
#pragma unroll 4
        for (int i = 0; i < 32; i++) {
            const size_t idx = (((size_t)xb * 32 + i) * 256 + t) * 4;
            float4 v = *(const float4*)(X + idx);
            half4v h = {(_Float16)v.x, (_Float16)v.y, (_Float16)v.z, (_Float16)v.w};
            *(half4v*)(Xh + idx) = h;
        }
    }
}

// ---------------------------------------------------------------------------
// k1: projection + attention logits. Per (b,h): P[1024,64] = X_b @ W_h.
// NO LDS / NO barriers in the K-loop: A/B MFMA fragments loaded directly from
// global (fp16). Epilogue: Pt[bh][o][n] fp16 (LDS transpose), s/t from fp32
// accumulators (shuffle-reduce), per-tile tmax.
// grid (N/64, B*H), block 256 (4 waves).
// ---------------------------------------------------------------------------
__global__ __launch_bounds__(256) void k1_proj(const _Float16* __restrict__ Xh,
                                               const _Float16* __restrict__ Wt,
                                               const float* __restrict__ w1,
                                               const float* __restrict__ b1,
                                               const float* __restrict__ w2,
                                               const float* __restrict__ b2,
                                               _Float16* __restrict__ Pt,
                                               float* __restrict__ s_g,
                                               float* __restrict__ t_g,
                                               float* __restrict__ tmax16) {
    __shared__ __align__(16) _Float16 po[64 * 72];
    __shared__ float tred[64];

    const int bh = blockIdx.y;
    const int b  = bh >> 3;
    const int h  = bh & 7;
    const int n0 = blockIdx.x * 64;
    const int t    = threadIdx.x;
    const int wave = t >> 6;
    const int lane = t & 63;
    const int quad = lane >> 4;
    const int l15  = lane & 15;

    floatx4 acc[4];
#pragma unroll
    for (int i = 0; i < 4; i++) acc[i] = {0.f, 0.f, 0.f, 0.f};

    float w1v[4], w2v[4];
#pragma unroll
    for (int ct = 0; ct < 4; ct++) {
        w1v[ct] = w1[h * 64 + ct * 16 + l15];
        w2v[ct] = w2[h * 64 + ct * 16 + l15];
    }
    const float b1h = b1[h];
    const float b2h = b2[h];

    // direct-global fragment pointers (same per-lane values the LDS path fed)
    const _Float16* xf = Xh + ((size_t)(b * NN + n0 + wave * 16 + l15)) * IN_DIM + quad * 8;
    const _Float16* wf = Wt + ((size_t)(h * SUP + l15)) * IN_DIM + quad * 8;

#pragma unroll 4
    for (int k0 = 0; k0 < IN_DIM; k0 += 32) {
        half8 af  = *(const half8*)(xf + k0);
        half8 bf0 = *(const half8*)(wf + k0);
        half8 bf1 = *(const half8*)(wf + 16 * IN_DIM + k0);
        half8 bf2 = *(const half8*)(wf + 32 * IN_DIM + k0);
        half8 bf3 = *(const half8*)(wf + 48 * IN_DIM + k0);
        acc[0] = __builtin_amdgcn_mfma_f32_16x16x32_f16(af, bf0, acc[0], 0, 0, 0);
        acc[1] = __builtin_amdgcn_mfma_f32_16x16x32_f16(af, bf1, acc[1], 0, 0, 0);
        acc[2] = __builtin_amdgcn_mfma_f32_16x16x32_f16(af, bf2, acc[2], 0, 0, 0);
        acc[3] = __builtin_amdgcn_mfma_f32_16x16x32_f16(af, bf3, acc[3], 0, 0, 0);
    }

    // epilogue 1: po[o][n] fp16 tile + s/t from fp32 accumulators
#pragma unroll
    for (int ct = 0; ct < 4; ct++) {
#pragma unroll
        for (int r = 0; r < 4; r++) {
            int o = ct * 16 + l15;
            int n = wave * 16 + quad * 4 + r;
            po[o * 72 + n] = (_Float16)acc[ct][r];
        }
    }
#pragma unroll
    for (int r = 0; r < 4; r++) {
        float sp = 0.f, tp = 0.f;
#pragma unroll
        for (int ct = 0; ct < 4; ct++) {
            sp += acc[ct][r] * w1v[ct];
            tp += acc[ct][r] * w2v[ct];
        }
#pragma unroll
        for (int off = 1; off < 16; off <<= 1) {
            sp += __shfl_xor(sp, off);
            tp += __shfl_xor(tp, off);
        }
        if (l15 == 0) {
            const int n = wave * 16 + quad * 4 + r;
            s_g[(size_t)bh * NN + n0 + n] = sp + b1h;
            float tv = tp + b2h;
            t_g[(size_t)bh * NN + n0 + n] = tv;
            tred[n] = tv;
        }
    }
    __syncthreads();
    // epilogue 2: coalesced Pt store
    {
        const int o   = t >> 2;
        const int nof = (t & 3) * 16;
        _Float16* dst = Pt + ((size_t)bh * SUP + o) * NN + n0 + nof;
        *(half8*)dst       = *(const half8*)&po[o * 72 + nof];
        *(half8*)(dst + 8) = *(const half8*)&po[o * 72 + nof + 8];
    }
    if (t == 0) {
        float m = -1e30f;
#pragma unroll
        for (int i = 0; i < 64; i++) m = fmaxf(m, tred[i]);
        tmax16[bh * 16 + blockIdx.x] = m;
    }
}

// ---------------------------------------------------------------------------
// k2: fused masked-softmax attention + aggregation, packed-fp16 logit math.
// Per block: one (b,h), 128 query rows, 512 threads (8 waves).
// Double-buffered 128-key V^T tiles, ONE barrier per tile. Mask bits expanded
// via 256-entry LDS LUT; Z via v_dot2_f32_f16 + shfl.
// grid (N/128, B*H), block 512.
// ---------------------------------------------------------------------------
__global__ __launch_bounds__(512) void k2_attn(const unsigned char* __restrict__ Am,
                                               const _Float16* __restrict__ Pt,
                                               const float* __restrict__ s_g,
                                               const float* __restrict__ t_g,
                                               const float* __restrict__ tmax16,
                                               float* __restrict__ out) {
    __shared__ __align__(16) _Float16 vts[2][64 * 136];  // V^T tile [o][m], pad 8
    __shared__ __align__(16) unsigned t2l[NN / 2];       // t as packed half2 (2 KB)
    __shared__ __align__(16) uint4 lutm[256];            // bit->fp16-mask-word LUT (4 KB)

    const int bh = blockIdx.y;
    const int b  = bh >> 3;
    const int h  = bh & 7;
    const int n0 = blockIdx.x * 128;
    const int t    = threadIdx.x;
    const int wave = t >> 6;
    const int lane = t & 63;
    const int quad = lane >> 4;
    const int l15  = lane & 15;
    const int row4 = t >> 3;   // staging o-row 0..63
    const int seg  = t & 7;    // staging segment (16 keys each)

    // stage t as packed fp16 pairs
    {
        float2 tv2 = ((const float2*)(t_g + (size_t)bh * NN))[t];
        half2v tp = {(_Float16)tv2.x, (_Float16)tv2.y};
        t2l[t] = *(unsigned*)&tp;
    }
    // build mask-expansion LUT: byte -> 4 words of per-half 0xFFFF masks
    if (t < 256) {
        unsigned e = (unsigned)t;
        uint4 v;
        v.x = ((e & 1u)   ? 0xFFFFu : 0u) | ((e & 2u)   ? 0xFFFF0000u : 0u);
        v.y = ((e & 4u)   ? 0xFFFFu : 0u) | ((e & 8u)   ? 0xFFFF0000u : 0u);
        v.z = ((e & 16u)  ? 0xFFFFu : 0u) | ((e & 32u)  ? 0xFFFF0000u : 0u);
        v.w = ((e & 64u)  ? 0xFFFFu : 0u) | ((e & 128u) ? 0xFFFF0000u : 0u);
        lutm[t] = v;
    }

    float tmax = -1e30f;
#pragma unroll
    for (int i = 0; i < 16; i++) tmax = fmaxf(tmax, tmax16[bh * 16 + i]);

    const int myrow = wave * 16 + l15;                 // this lane's query row (0..127)
    const float sv = s_g[(size_t)bh * NN + n0 + myrow];
    const float xc = sv + tmax;
    const float cv = fmaxf(xc, 0.01f * xc);            // c >= row max logit
    const float l2e = 1.44269504f;
    const _Float16 sc1h = (_Float16)((sv - cv) * l2e);       // (s-c)*log2e
    const _Float16 sc2h = (_Float16)(-0.99f * cv * l2e);     // -0.99*c*log2e
    const half2v sc1 = {sc1h, sc1h};
    const half2v sc2 = {sc2h, sc2h};
    const half2v vl2e = {(_Float16)l2e, (_Float16)l2e};
    const half2v v001 = {(_Float16)0.01f, (_Float16)0.01f};
    const half2v ones2 = {(_Float16)1.0f, (_Float16)1.0f};

    floatx4 acc[4];
#pragma unroll
    for (int i = 0; i < 4; i++) acc[i] = {0.f, 0.f, 0.f, 0.f};
    float zp = 0.f;

    // V^T staging pointer + prefetch tile 0
    const _Float16* pb = Pt + ((size_t)bh * SUP + row4) * NN + seg * 16;
    half8 v0 = ((const half8*)pb)[0];
    half8 v1 = ((const half8*)pb)[1];
    // mask row pointer + prefetch tile 0
    const uint4* mrow = (const uint4*)(Am + ((size_t)b * NN + n0 + myrow) * 128);
    uint4 mcur = mrow[0];

    for (int mt = 0; mt < 8; mt++) {
        const int cur = mt & 1;
        {
            _Float16* d = &vts[cur][row4 * 136 + seg * 16];
            ((half8*)d)[0] = v0;
            ((half8*)d)[1] = v1;
        }
        __syncthreads();   // tile mt (and t2l/lutm on mt=0) visible; buf reads drained
        uint4 mnext;
        if (mt < 7) {
            const _Float16* p = pb + (mt + 1) * 128;
            v0 = ((const half8*)p)[0];
            v1 = ((const half8*)p)[1];
            mnext = mrow[mt + 1];
        }
        const unsigned mw[4] = {mcur.x, mcur.y, mcur.z, mcur.w};
#pragma unroll
        for (int kk = 0; kk < 4; kk++) {
            const unsigned mbyte = (mw[kk] >> (quad * 8)) & 0xffu;
            uint4 mx = lutm[mbyte];
            const unsigned mxw[4] = {mx.x, mx.y, mx.z, mx.w};
            uint4 tw = *(const uint4*)&t2l[mt * 64 + kk * 16 + quad * 4];
            union { uint4 u; half2v h[4]; } tt; tt.u = tw;
            union { half2v h[4]; half8 h8; } wbu;
#pragma unroll
            for (int p = 0; p < 4; p++) {
                half2v y = tt.h[p] * vl2e + sc1;                    // (x-c)*log2e
                half2v w = y * v001 + sc2;                          // (.01x-c)*log2e
                half2v z = __builtin_elementwise_max(y, w);         // lrelu branch merge
                __half2 zz = *(__half2*)&z;
                __half2 ee = h2exp2(zz);                            // 2^z = e^(l-c)
                unsigned eb = (*(unsigned*)&ee) & mxw[p];           // mask
                half2v e2 = *(half2v*)&eb;
#if __has_builtin(__builtin_amdgcn_fdot2)
                zp = __builtin_amdgcn_fdot2(e2, ones2, zp, false);
#else
                zp += (float)e2.x + (float)e2.y;
#endif
                wbu.h[p] = e2;
            }
            half8 af = wbu.h8;
#pragma unroll
            for (int ct = 0; ct < 4; ct++) {
                half8 bf = *(const half8*)&vts[cur][(ct * 16 + l15) * 136 + kk * 32 + quad * 8];
                acc[ct] = __builtin_amdgcn_mfma_f32_16x16x32_f16(af, bf, acc[ct], 0, 0, 0);
            }
        }
        if (mt < 7) mcur = mnext;
    }

    // Z reduction across quads, distribute 1/Z by shfl
    zp += __shfl_xor(zp, 16);
    zp += __shfl_xor(zp, 32);
    const float rzown = 1.0f / zp;

    // epilogue: out[b][n][h*64+o] = relu(acc / Z)
#pragma unroll
    for (int r = 0; r < 4; r++) {
        const int rr = wave * 16 + quad * 4 + r;
        const float rz = __shfl(rzown, quad * 20 + r);
#pragma unroll
        for (int ct = 0; ct < 4; ct++) {
            float v = acc[ct][r] * rz;
            v = v > 0.f ? v : 0.f;
            out[((size_t)b * NN + n0 + rr) * HS + h * SUP + ct * 16 + l15] = v;
        }
    }
}

// ---------------------------------------------------------------------------
extern "C" void kernel_launch(void* const* d_in, const int* in_sizes, int n_in,
                              void* d_out, int out_size, void* d_ws, size_t ws_size,
                              hipStream_t stream) {
    const float* A  = (const float*)d_in[0];
    const float* X  = (const float*)d_in[1];
    const float* W  = (const float*)d_in[2];
    const float* w1 = (const float*)d_in[3];
    const float* b1 = (const float*)d_in[4];
    const float* w2 = (const float*)d_in[5];
    const float* b2 = (const float*)d_in[6];
    float* out = (float*)d_out;

    char* ws = (char*)d_ws;
    _Float16*      Wt     = (_Float16*)(ws);                  // 524288 B
    _Float16*      Pt     = (_Float16*)(ws + 524288);         // 8388608 B
    float*         s_g    = (float*)(ws + 8912896);           // 262144 B
    float*         t_g    = (float*)(ws + 9175040);           // 262144 B
    float*         tmax16 = (float*)(ws + 9437184);           // 4096 B
    unsigned char* Am     = (unsigned char*)(ws + 9441280);   // 1048576 B
    _Float16*      Xh     = (_Float16*)(ws + 10489856);       // 8388608 B

    hipLaunchKernelGGL(kprep, dim3(2048 + 64 + 128), dim3(256), 0, stream, A, Am, W, Wt, X, Xh);
    hipLaunchKernelGGL(k1_proj, dim3(NN / 64, BB * HH), dim3(256), 0, stream,
                       Xh, Wt, w1, b1, w2, b2, Pt, s_g, t_g, tmax16);
    hipLaunchKernelGGL(k2_attn, dim3(NN / 128, BB * HH), dim3(512), 0, stream,
                       Am, Pt, s_g, t_g, tmax16, out);
}

// Round 5
// 137.211 us; speedup vs baseline: 1.1633x; 1.1633x over previous
//
#include <hip/hip_runtime.h>
#include <hip/hip_fp16.h>

// Problem constants (match reference)
#define BB 8
#define NN 1024
#define IN_DIM 512
#define HH 8
#define SUP 64
#define HS (HH * SUP)   // 512

typedef _Float16 half8 __attribute__((ext_vector_type(8)));
typedef _Float16 half4v __attribute__((ext_vector_type(4)));
typedef _Float16 half2v __attribute__((ext_vector_type(2)));
typedef float floatx4 __attribute__((ext_vector_type(4)));

// ---------------------------------------------------------------------------
// kprep: grid-split kernel.
//   [0,2048):    pack A[b][n][m] fp32 (0/1) -> bitmask Am[row][128 B]
//   [2048,2112): W[h][i][o] fp32 -> Wt[h][o][i] fp16 (transpose+cvt)
//   [2112,2240): X fp32 -> Xh fp16 (straight cast, same layout)
// block 256.
// ---------------------------------------------------------------------------
__global__ __launch_bounds__(256) void kprep(const float* __restrict__ A,
                                             unsigned char* __restrict__ Am,
                                             const float* __restrict__ W,
                                             _Float16* __restrict__ Wt,
                                             const float* __restrict__ X,
                                             _Float16* __restrict__ Xh) {
    __shared__ float tile[64][65];
    const int bid = blockIdx.x;
    const int t   = threadIdx.x;
    if (bid < 2048) {
        // ---- pack A ----
        const int gw   = bid * 4 + (t >> 6);   // row = b*N+n
        const int lane = t & 63;
        const float* arow = A + (size_t)gw * NN;
        unsigned long long keep = 0;
#pragma unroll
        for (int g = 0; g < 16; g++) {
            float a = arow[g * 64 + lane];
            unsigned long long bal = __ballot(a > 0.5f);
            if (lane == g) keep = bal;
        }
        if (lane < 16)
            *(unsigned long long*)(Am + (size_t)gw * 128 + lane * 8) = keep;
    } else if (bid < 2112) {
        // ---- transpose W ----
        const int wb = bid - 2048;
        const int it = wb & 7;
        const int h  = wb >> 3;
        {
            const int i  = t >> 2;
            const int o0 = (t & 3) * 16;
            const float* src = W + ((size_t)h * IN_DIM + it * 64 + i) * SUP + o0;
#pragma unroll
            for (int j = 0; j < 4; j++) {
                float4 v = ((const float4*)src)[j];
                tile[i][o0 + j * 4 + 0] = v.x;
                tile[i][o0 + j * 4 + 1] = v.y;
                tile[i][o0 + j * 4 + 2] = v.z;
                tile[i][o0 + j * 4 + 3] = v.w;
            }
        }
        __syncthreads();
        {
            const int o  = t >> 2;
            const int i0 = (t & 3) * 16;
            _Float16 buf[16];
#pragma unroll
            for (int j = 0; j < 16; j++) buf[j] = (_Float16)tile[i0 + j][o];
            _Float16* dst = Wt + ((size_t)h * SUP + o) * IN_DIM + it * 64 + i0;
            *(half8*)dst       = *(half8*)buf;
            *(half8*)(dst + 8) = *(half8*)(buf + 8);
        }
    } else {
        // ---- X fp32 -> fp16 ----  4,194,304 elems / 128 blocks / 256 thr
        const int xb = bid - 2112;
#pragma unroll 4
        for (int i = 0; i < 32; i++) {
            const size_t idx = (((size_t)xb * 32 + i) * 256 + t) * 4;
            float4 v = *(const float4*)(X + idx);
            half4v h = {(_Float16)v.x, (_Float16)v.y, (_Float16)v.z, (_Float16)v.w};
            *(half4v*)(Xh + idx) = h;
        }
    }
}

// ---------------------------------------------------------------------------
// k1: projection + attention logits. Per (b,h): P[1024,64] = X_b @ W_h.
// LDS double-buffered (R3 structure), fp16 inputs: ONE 16B load per thread
// per K-slab, ONE barrier per slab, register prefetch. Epilogue: Pt[bh][o][n]
// fp16 (LDS transpose), s/t from fp32 accumulators, per-tile tmax.
// grid (N/64, B*H), block 256 (4 waves).
// ---------------------------------------------------------------------------
__global__ __launch_bounds__(256) void k1_proj(const _Float16* __restrict__ Xh,
                                               const _Float16* __restrict__ Wt,
                                               const float* __restrict__ w1,
                                               const float* __restrict__ b1,
                                               const float* __restrict__ w2,
                                               const float* __restrict__ b2,
                                               _Float16* __restrict__ Pt,
                                               float* __restrict__ s_g,
                                               float* __restrict__ t_g,
                                               float* __restrict__ tmax16) {
    __shared__ __align__(16) _Float16 xs[2][64 * 40];   // [n][k] pad-40
    __shared__ __align__(16) _Float16 wsh[2][64 * 40];  // [o][k] pad-40
    __shared__ __align__(16) _Float16 po[64 * 72];
    __shared__ float tred[64];

    const int bh = blockIdx.y;
    const int b  = bh >> 3;
    const int h  = bh & 7;
    const int n0 = blockIdx.x * 64;
    const int t    = threadIdx.x;
    const int wave = t >> 6;
    const int lane = t & 63;
    const int quad = lane >> 4;
    const int l15  = lane & 15;
    const int row  = t >> 2;
    const int koff = (t & 3) * 8;

    floatx4 acc[4];
#pragma unroll
    for (int i = 0; i < 4; i++) acc[i] = {0.f, 0.f, 0.f, 0.f};

    float w1v[4], w2v[4];
#pragma unroll
    for (int ct = 0; ct < 4; ct++) {
        w1v[ct] = w1[h * 64 + ct * 16 + l15];
        w2v[ct] = w2[h * 64 + ct * 16 + l15];
    }
    const float b1h = b1[h];
    const float b2h = b2[h];

    const _Float16* xbase = Xh + ((size_t)b * NN + n0 + row) * IN_DIM + koff;
    const _Float16* wbase = Wt + ((size_t)h * SUP + row) * IN_DIM + koff;

    // prefetch slab 0
    half8 xv = *(const half8*)xbase;
    half8 wv = *(const half8*)wbase;

    for (int it = 0; it < 16; it++) {
        const int cur = it & 1;
        *(half8*)&xs[cur][row * 40 + koff]  = xv;
        *(half8*)&wsh[cur][row * 40 + koff] = wv;
        __syncthreads();   // tile `it` visible; prior reads of buf `cur` drained
        if (it < 15) {
            xv = *(const half8*)(xbase + (it + 1) * 32);
            wv = *(const half8*)(wbase + (it + 1) * 32);
        }
        half8 af = *(const half8*)&xs[cur][(wave * 16 + l15) * 40 + quad * 8];
#pragma unroll
        for (int ct = 0; ct < 4; ct++) {
            half8 bf = *(const half8*)&wsh[cur][(ct * 16 + l15) * 40 + quad * 8];
            acc[ct] = __builtin_amdgcn_mfma_f32_16x16x32_f16(af, bf, acc[ct], 0, 0, 0);
        }
        // no second barrier: next write goes to the other buffer
    }
    __syncthreads();

    // epilogue 1: po[o][n] fp16 tile + s/t from fp32 accumulators
#pragma unroll
    for (int ct = 0; ct < 4; ct++) {
#pragma unroll
        for (int r = 0; r < 4; r++) {
            int o = ct * 16 + l15;
            int n = wave * 16 + quad * 4 + r;
            po[o * 72 + n] = (_Float16)acc[ct][r];
        }
    }
#pragma unroll
    for (int r = 0; r < 4; r++) {
        float sp = 0.f, tp = 0.f;
#pragma unroll
        for (int ct = 0; ct < 4; ct++) {
            sp += acc[ct][r] * w1v[ct];
            tp += acc[ct][r] * w2v[ct];
        }
#pragma unroll
        for (int off = 1; off < 16; off <<= 1) {
            sp += __shfl_xor(sp, off);
            tp += __shfl_xor(tp, off);
        }
        if (l15 == 0) {
            const int n = wave * 16 + quad * 4 + r;
            s_g[(size_t)bh * NN + n0 + n] = sp + b1h;
            float tv = tp + b2h;
            t_g[(size_t)bh * NN + n0 + n] = tv;
            tred[n] = tv;
        }
    }
    __syncthreads();
    // epilogue 2: coalesced Pt store
    {
        const int o   = t >> 2;
        const int nof = (t & 3) * 16;
        _Float16* dst = Pt + ((size_t)bh * SUP + o) * NN + n0 + nof;
        *(half8*)dst       = *(const half8*)&po[o * 72 + nof];
        *(half8*)(dst + 8) = *(const half8*)&po[o * 72 + nof + 8];
    }
    if (t == 0) {
        float m = -1e30f;
#pragma unroll
        for (int i = 0; i < 64; i++) m = fmaxf(m, tred[i]);
        tmax16[bh * 16 + blockIdx.x] = m;
    }
}

// ---------------------------------------------------------------------------
// k2: fused masked-softmax attention + aggregation, packed-fp16 logit math.
// Per block: one (b,h), 128 query rows, 512 threads (8 waves).
// Double-buffered 128-key V^T tiles, ONE barrier per tile. Mask bits expanded
// via 256-entry LDS LUT; Z via v_dot2_f32_f16 + shfl.
// grid (N/128, B*H), block 512.
// ---------------------------------------------------------------------------
__global__ __launch_bounds__(512) void k2_attn(const unsigned char* __restrict__ Am,
                                               const _Float16* __restrict__ Pt,
                                               const float* __restrict__ s_g,
                                               const float* __restrict__ t_g,
                                               const float* __restrict__ tmax16,
                                               float* __restrict__ out) {
    __shared__ __align__(16) _Float16 vts[2][64 * 136];  // V^T tile [o][m], pad 8
    __shared__ __align__(16) unsigned t2l[NN / 2];       // t as packed half2 (2 KB)
    __shared__ __align__(16) uint4 lutm[256];            // bit->fp16-mask-word LUT (4 KB)

    const int bh = blockIdx.y;
    const int b  = bh >> 3;
    const int h  = bh & 7;
    const int n0 = blockIdx.x * 128;
    const int t    = threadIdx.x;
    const int wave = t >> 6;
    const int lane = t & 63;
    const int quad = lane >> 4;
    const int l15  = lane & 15;
    const int row4 = t >> 3;   // staging o-row 0..63
    const int seg  = t & 7;    // staging segment (16 keys each)

    // stage t as packed fp16 pairs
    {
        float2 tv2 = ((const float2*)(t_g + (size_t)bh * NN))[t];
        half2v tp = {(_Float16)tv2.x, (_Float16)tv2.y};
        t2l[t] = *(unsigned*)&tp;
    }
    // build mask-expansion LUT: byte -> 4 words of per-half 0xFFFF masks
    if (t < 256) {
        unsigned e = (unsigned)t;
        uint4 v;
        v.x = ((e & 1u)   ? 0xFFFFu : 0u) | ((e & 2u)   ? 0xFFFF0000u : 0u);
        v.y = ((e & 4u)   ? 0xFFFFu : 0u) | ((e & 8u)   ? 0xFFFF0000u : 0u);
        v.z = ((e & 16u)  ? 0xFFFFu : 0u) | ((e & 32u)  ? 0xFFFF0000u : 0u);
        v.w = ((e & 64u)  ? 0xFFFFu : 0u) | ((e & 128u) ? 0xFFFF0000u : 0u);
        lutm[t] = v;
    }

    float tmax = -1e30f;
#pragma unroll
    for (int i = 0; i < 16; i++) tmax = fmaxf(tmax, tmax16[bh * 16 + i]);

    const int myrow = wave * 16 + l15;                 // this lane's query row (0..127)
    const float sv = s_g[(size_t)bh * NN + n0 + myrow];
    const float xc = sv + tmax;
    const float cv = fmaxf(xc, 0.01f * xc);            // c >= row max logit
    const float l2e = 1.44269504f;
    const _Float16 sc1h = (_Float16)((sv - cv) * l2e);       // (s-c)*log2e
    const _Float16 sc2h = (_Float16)(-0.99f * cv * l2e);     // -0.99*c*log2e
    const half2v sc1 = {sc1h, sc1h};
    const half2v sc2 = {sc2h, sc2h};
    const half2v vl2e = {(_Float16)l2e, (_Float16)l2e};
    const half2v v001 = {(_Float16)0.01f, (_Float16)0.01f};
    const half2v ones2 = {(_Float16)1.0f, (_Float16)1.0f};

    floatx4 acc[4];
#pragma unroll
    for (int i = 0; i < 4; i++) acc[i] = {0.f, 0.f, 0.f, 0.f};
    float zp = 0.f;

    // V^T staging pointer + prefetch tile 0
    const _Float16* pb = Pt + ((size_t)bh * SUP + row4) * NN + seg * 16;
    half8 v0 = ((const half8*)pb)[0];
    half8 v1 = ((const half8*)pb)[1];
    // mask row pointer + prefetch tile 0
    const uint4* mrow = (const uint4*)(Am + ((size_t)b * NN + n0 + myrow) * 128);
    uint4 mcur = mrow[0];

    for (int mt = 0; mt < 8; mt++) {
        const int cur = mt & 1;
        {
            _Float16* d = &vts[cur][row4 * 136 + seg * 16];
            ((half8*)d)[0] = v0;
            ((half8*)d)[1] = v1;
        }
        __syncthreads();   // tile mt (and t2l/lutm on mt=0) visible
        uint4 mnext;
        if (mt < 7) {
            const _Float16* p = pb + (mt + 1) * 128;
            v0 = ((const half8*)p)[0];
            v1 = ((const half8*)p)[1];
            mnext = mrow[mt + 1];
        }
        const unsigned mw[4] = {mcur.x, mcur.y, mcur.z, mcur.w};
#pragma unroll
        for (int kk = 0; kk < 4; kk++) {
            const unsigned mbyte = (mw[kk] >> (quad * 8)) & 0xffu;
            uint4 mx = lutm[mbyte];
            const unsigned mxw[4] = {mx.x, mx.y, mx.z, mx.w};
            uint4 tw = *(const uint4*)&t2l[mt * 64 + kk * 16 + quad * 4];
            union { uint4 u; half2v h[4]; } tt; tt.u = tw;
            union { half2v h[4]; half8 h8; } wbu;
#pragma unroll
            for (int p = 0; p < 4; p++) {
                half2v y = tt.h[p] * vl2e + sc1;                    // (x-c)*log2e
                half2v w = y * v001 + sc2;                          // (.01x-c)*log2e
                half2v z = __builtin_elementwise_max(y, w);         // lrelu branch merge
                __half2 zz = *(__half2*)&z;
                __half2 ee = h2exp2(zz);                            // 2^z = e^(l-c)
                unsigned eb = (*(unsigned*)&ee) & mxw[p];           // mask
                half2v e2 = *(half2v*)&eb;
#if __has_builtin(__builtin_amdgcn_fdot2)
                zp = __builtin_amdgcn_fdot2(e2, ones2, zp, false);
#else
                zp += (float)e2.x + (float)e2.y;
#endif
                wbu.h[p] = e2;
            }
            half8 af = wbu.h8;
#pragma unroll
            for (int ct = 0; ct < 4; ct++) {
                half8 bf = *(const half8*)&vts[cur][(ct * 16 + l15) * 136 + kk * 32 + quad * 8];
                acc[ct] = __builtin_amdgcn_mfma_f32_16x16x32_f16(af, bf, acc[ct], 0, 0, 0);
            }
        }
        if (mt < 7) mcur = mnext;
    }

    // Z reduction across quads, distribute 1/Z by shfl
    zp += __shfl_xor(zp, 16);
    zp += __shfl_xor(zp, 32);
    const float rzown = 1.0f / zp;

    // epilogue: out[b][n][h*64+o] = relu(acc / Z)
#pragma unroll
    for (int r = 0; r < 4; r++) {
        const int rr = wave * 16 + quad * 4 + r;
        const float rz = __shfl(rzown, quad * 20 + r);
#pragma unroll
        for (int ct = 0; ct < 4; ct++) {
            float v = acc[ct][r] * rz;
            v = v > 0.f ? v : 0.f;
            out[((size_t)b * NN + n0 + rr) * HS + h * SUP + ct * 16 + l15] = v;
        }
    }
}

// ---------------------------------------------------------------------------
extern "C" void kernel_launch(void* const* d_in, const int* in_sizes, int n_in,
                              void* d_out, int out_size, void* d_ws, size_t ws_size,
                              hipStream_t stream) {
    const float* A  = (const float*)d_in[0];
    const float* X  = (const float*)d_in[1];
    const float* W  = (const float*)d_in[2];
    const float* w1 = (const float*)d_in[3];
    const float* b1 = (const float*)d_in[4];
    const float* w2 = (const float*)d_in[5];
    const float* b2 = (const float*)d_in[6];
    float* out = (float*)d_out;

    char* ws = (char*)d_ws;
    _Float16*      Wt     = (_Float16*)(ws);                  // 524288 B
    _Float16*      Pt     = (_Float16*)(ws + 524288);         // 8388608 B
    float*         s_g    = (float*)(ws + 8912896);           // 262144 B
    float*         t_g    = (float*)(ws + 9175040);           // 262144 B
    float*         tmax16 = (float*)(ws + 9437184);           // 4096 B
    unsigned char* Am     = (unsigned char*)(ws + 9441280);   // 1048576 B
    _Float16*      Xh     = (_Float16*)(ws + 10489856);       // 8388608 B

    hipLaunchKernelGGL(kprep, dim3(2048 + 64 + 128), dim3(256), 0, stream, A, Am, W, Wt, X, Xh);
    hipLaunchKernelGGL(k1_proj, dim3(NN / 64, BB * HH), dim3(256), 0, stream,
                       Xh, Wt, w1, b1, w2, b2, Pt, s_g, t_g, tmax16);
    hipLaunchKernelGGL(k2_attn, dim3(NN / 128, BB * HH), dim3(512), 0, stream,
                       Am, Pt, s_g, t_g, tmax16, out);
}